// Round 3
// baseline (669.775 us; speedup 1.0000x reference)
//
#include <hip/hip_runtime.h>
#include <stdint.h>

#define BATCH 4096
#define FEAT  40960
#define H1    512
#define H2    256

typedef float f32x4 __attribute__((ext_vector_type(4)));
typedef short s16x8 __attribute__((ext_vector_type(8)));
typedef unsigned int u32x2 __attribute__((ext_vector_type(2)));
typedef unsigned int u32x4 __attribute__((ext_vector_type(4)));

// round-to-nearest-even f32 -> bf16, packed pair (lo in low 16 bits)
__device__ __forceinline__ unsigned bfpack2(float lo, float hi) {
  unsigned a = __float_as_uint(lo);
  unsigned b = __float_as_uint(hi);
  a += 0x7FFFu + ((a >> 16) & 1u);
  b += 0x7FFFu + ((b >> 16) & 1u);
  return (a >> 16) | (b & 0xFFFF0000u);
}

// Swizzled LDS byte offset for tiles with 64B row stride (32 bf16 per row).
// Bijective per 8-row stripe; same function on write and read; permutes only
// row bit0 and byte bits 4-5, so 8B/16B chunks stay aligned and consistent.
__device__ __forceinline__ int lds_off(int r, int kb) {
  return ((r ^ ((r >> 2) & 1)) << 6) + (kb ^ ((r & 3) << 4));
}

// Raw workgroup barrier that does NOT drain vmcnt (keeps prefetch loads in
// flight) but IS a hard compile-time scheduling fence on both sides, so LDS
// reads cannot be hoisted above it nor writes sunk below it (guide rule #18).
__device__ __forceinline__ void pipe_barrier() {
  asm volatile("s_waitcnt lgkmcnt(0)" ::: "memory");
  __builtin_amdgcn_sched_barrier(0);
  __builtin_amdgcn_s_barrier();
  __builtin_amdgcn_sched_barrier(0);
}

// ---------------------------------------------------------------------------
// Kernel 1: feature-transform GEMM, split-K partials.
// C_partial[ks][p][row][n] = A_p[row, kchunk] * ftw[n, kchunk]^T
// BM=128 BN=512 BK=32, 512 threads (8 waves as 2x4), fp32->bf16 reg-staged.
// ---------------------------------------------------------------------------
__global__ __launch_bounds__(512, 2)
void ft_gemm_kernel(const float* __restrict__ whiteF,
                    const float* __restrict__ blackF,
                    const float* __restrict__ ftw,
                    float* __restrict__ Ppart, int KS) {
  __shared__ char smem[81920];  // 2 buffers x (A 8KB + W 32KB)

  const int tid = threadIdx.x;
  const int bid = blockIdx.x;
  const int ks  = bid >> 6;         // k-split
  const int p   = bid & 1;          // perspective
  const int mt  = (bid >> 1) & 31;  // m-tile

  const float* Ag = (p == 0 ? whiteF : blackF) + (size_t)(mt * 128) * FEAT;
  const int kchunk = FEAT / KS;     // multiple of 32
  const int k0     = ks * kchunk;
  const int nsteps = kchunk >> 5;

  // staging decomposition
  const int a_row = tid >> 2, a_kq = tid & 3;   // A: 128 rows x 4 quads of 8 f32
  const int w_row = tid >> 3, w_kq = tid & 7;   // W: 64 rows/pass x 8 quads of 4 f32

  const float* aptr = Ag  + (size_t)a_row * FEAT + k0 + a_kq * 8;
  const float* wptr = ftw + (size_t)w_row * FEAT + k0 + w_kq * 4;

  f32x4 ra0, ra1, rw[8];
  auto issue = [&](int t) {
    const float* ap = aptr + t * 32;
    ra0 = *(const f32x4*)ap;
    ra1 = *(const f32x4*)(ap + 4);
    const float* wp = wptr + t * 32;
#pragma unroll
    for (int s = 0; s < 8; ++s)
      rw[s] = *(const f32x4*)(wp + (size_t)s * 64 * FEAT);
  };

  const int aoff_w = lds_off(a_row, a_kq * 16);
  int woff_w[8];
#pragma unroll
  for (int s = 0; s < 8; ++s)
    woff_w[s] = 8192 + lds_off(s * 64 + w_row, w_kq * 8);

  auto cvtwrite = [&](int b) {
    char* base = smem + b * 40960;
    u32x4 av;
    av.x = bfpack2(ra0.x, ra0.y); av.y = bfpack2(ra0.z, ra0.w);
    av.z = bfpack2(ra1.x, ra1.y); av.w = bfpack2(ra1.z, ra1.w);
    *(u32x4*)(base + aoff_w) = av;
#pragma unroll
    for (int s = 0; s < 8; ++s) {
      u32x2 wv;
      wv.x = bfpack2(rw[s].x, rw[s].y);
      wv.y = bfpack2(rw[s].z, rw[s].w);
      *(u32x2*)(base + woff_w[s]) = wv;
    }
  };

  // wave decomposition: 2 (M) x 4 (N); wave tile 64 x 128
  const int lane = tid & 63, wave = tid >> 6;
  const int wm = wave >> 2, wn = wave & 3;
  const int lrow = lane & 15, lkb = (lane >> 4) * 16;

  int a_off[4], b_off[8];
#pragma unroll
  for (int m = 0; m < 4; ++m) a_off[m] = lds_off(wm * 64 + m * 16 + lrow, lkb);
#pragma unroll
  for (int n = 0; n < 8; ++n) b_off[n] = 8192 + lds_off(wn * 128 + n * 16 + lrow, lkb);

  f32x4 acc[4][8];
#pragma unroll
  for (int m = 0; m < 4; ++m)
#pragma unroll
    for (int n = 0; n < 8; ++n) acc[m][n] = (f32x4){0.f, 0.f, 0.f, 0.f};

  issue(0);
  for (int t = 0; t < nsteps; ++t) {
    const int b = t & 1;
    cvtwrite(b);                      // vmcnt waits auto-inserted for reg deps
    if (t + 1 < nsteps) issue(t + 1); // next-tile loads stay in flight
    pipe_barrier();                   // lgkmcnt(0) + s_barrier, sched-fenced
    char* base = smem + b * 40960;
    s16x8 af[4];
#pragma unroll
    for (int m = 0; m < 4; ++m) af[m] = *(const s16x8*)(base + a_off[m]);
#pragma unroll
    for (int n = 0; n < 8; ++n) {
      s16x8 bfn = *(const s16x8*)(base + b_off[n]);
#pragma unroll
      for (int m = 0; m < 4; ++m)
        acc[m][n] = __builtin_amdgcn_mfma_f32_16x16x32_bf16(af[m], bfn, acc[m][n], 0, 0, 0);
    }
  }

  // write partials: C/D frag mapping: col = lane&15, row = (lane>>4)*4 + reg
  float* Pp = Ppart + ((size_t)(ks * 2 + p) * BATCH + mt * 128) * H1;
  const int r0 = wm * 64 + (lane >> 4) * 4;
  const int c0 = wn * 128 + lrow;
#pragma unroll
  for (int m = 0; m < 4; ++m)
#pragma unroll
    for (int n = 0; n < 8; ++n) {
      float* dst = Pp + (size_t)(r0 + m * 16) * H1 + c0 + n * 16;
#pragma unroll
      for (int j = 0; j < 4; ++j) dst[(size_t)j * H1] = acc[m][n][j];
    }
}

// ---------------------------------------------------------------------------
// Kernel 2: reduce split-K partials + bias + clip[0,1] -> combined bf16
// combined[row][p*512 + n]
// ---------------------------------------------------------------------------
__global__ __launch_bounds__(256)
void ft_reduce_kernel(const float* __restrict__ Ppart,
                      const float* __restrict__ ftb,
                      unsigned short* __restrict__ comb, int KS) {
  const size_t gid = (size_t)blockIdx.x * 256 + threadIdx.x;  // over 2*B*H1/4
  const int    pp  = (int)(gid / (BATCH * H1 / 4));
  const size_t rem = gid % (BATCH * H1 / 4);
  const int    row = (int)(rem / (H1 / 4));
  const int    n4  = (int)(rem % (H1 / 4)) * 4;

  f32x4 s = (f32x4){0.f, 0.f, 0.f, 0.f};
  for (int ks = 0; ks < KS; ++ks)
    s += *(const f32x4*)(Ppart + ((size_t)(ks * 2 + pp) * BATCH + row) * H1 + n4);
  const f32x4 bv = *(const f32x4*)(ftb + n4);
  s += bv;
  s.x = fminf(fmaxf(s.x, 0.f), 1.f);
  s.y = fminf(fmaxf(s.y, 0.f), 1.f);
  s.z = fminf(fmaxf(s.z, 0.f), 1.f);
  s.w = fminf(fmaxf(s.w, 0.f), 1.f);

  u32x2 o;
  o.x = bfpack2(s.x, s.y);
  o.y = bfpack2(s.z, s.w);
  *(u32x2*)(comb + (size_t)row * 1024 + pp * H1 + n4) = o;
}

// ---------------------------------------------------------------------------
// Kernel 3: fc1 (bf16 MFMA) + relu + fc2 dot + bias -> out FLOAT32 [4096]
// BM=64, BN=256(full), K=1024; 256 threads = 4 waves (1xN split).
// ---------------------------------------------------------------------------
__global__ __launch_bounds__(256)
void fc_kernel(const unsigned short* __restrict__ comb,
               const float* __restrict__ w1, const float* __restrict__ b1,
               const float* __restrict__ w2, const float* __restrict__ b2,
               float* __restrict__ out) {
  __shared__ char smem[40960];  // 2 x (A 4KB + W 16KB)
  __shared__ float rowsum[64];

  const int tid = threadIdx.x;
  const int bm  = blockIdx.x;  // 64 blocks of 64 rows
  if (tid < 64) rowsum[tid] = 0.f;

  const int a_row = tid >> 2, a_kq = tid & 3;
  const unsigned short* aptr = comb + (size_t)(bm * 64 + a_row) * 1024 + a_kq * 8;
  const float* wptr = w1 + (size_t)a_row * 1024 + a_kq * 8;

  u32x4 raA;
  f32x4 rw0[4], rw1[4];
  auto issue = [&](int t) {
    raA = *(const u32x4*)(aptr + t * 32);
    const float* wp = wptr + t * 32;
#pragma unroll
    for (int s = 0; s < 4; ++s) {
      rw0[s] = *(const f32x4*)(wp + (size_t)s * 64 * 1024);
      rw1[s] = *(const f32x4*)(wp + (size_t)s * 64 * 1024 + 4);
    }
  };

  const int aoff_w = lds_off(a_row, a_kq * 16);
  int woff_w[4];
#pragma unroll
  for (int s = 0; s < 4; ++s)
    woff_w[s] = 4096 + lds_off(s * 64 + a_row, a_kq * 16);

  auto cvtwrite = [&](int b) {
    char* base = smem + b * 20480;
    *(u32x4*)(base + aoff_w) = raA;
#pragma unroll
    for (int s = 0; s < 4; ++s) {
      u32x4 wv;
      wv.x = bfpack2(rw0[s].x, rw0[s].y); wv.y = bfpack2(rw0[s].z, rw0[s].w);
      wv.z = bfpack2(rw1[s].x, rw1[s].y); wv.w = bfpack2(rw1[s].z, rw1[s].w);
      *(u32x4*)(base + woff_w[s]) = wv;
    }
  };

  const int lane = tid & 63, wn = tid >> 6;
  const int lrow = lane & 15, lkb = (lane >> 4) * 16;
  int a_off[4], b_off[4];
#pragma unroll
  for (int m = 0; m < 4; ++m) a_off[m] = lds_off(m * 16 + lrow, lkb);
#pragma unroll
  for (int n = 0; n < 4; ++n) b_off[n] = 4096 + lds_off(wn * 64 + n * 16 + lrow, lkb);

  f32x4 acc[4][4];
#pragma unroll
  for (int m = 0; m < 4; ++m)
#pragma unroll
    for (int n = 0; n < 4; ++n) acc[m][n] = (f32x4){0.f, 0.f, 0.f, 0.f};

  issue(0);
  for (int t = 0; t < 32; ++t) {
    const int b = t & 1;
    cvtwrite(b);
    if (t + 1 < 32) issue(t + 1);
    pipe_barrier();
    char* base = smem + b * 20480;
    s16x8 af[4];
#pragma unroll
    for (int m = 0; m < 4; ++m) af[m] = *(const s16x8*)(base + a_off[m]);
#pragma unroll
    for (int n = 0; n < 4; ++n) {
      s16x8 bfn = *(const s16x8*)(base + b_off[n]);
#pragma unroll
      for (int m = 0; m < 4; ++m)
        acc[m][n] = __builtin_amdgcn_mfma_f32_16x16x32_bf16(af[m], bfn, acc[m][n], 0, 0, 0);
    }
  }

  // epilogue: x = relu(acc + b1[col]); contribute x*w2[col] to row sums
  float b1v[4], w2v[4];
#pragma unroll
  for (int n = 0; n < 4; ++n) {
    const int col = wn * 64 + n * 16 + lrow;
    b1v[n] = b1[col];
    w2v[n] = w2[col];
  }
#pragma unroll
  for (int m = 0; m < 4; ++m)
#pragma unroll
    for (int j = 0; j < 4; ++j) {
      float v = 0.f;
#pragma unroll
      for (int n = 0; n < 4; ++n) {
        float x = acc[m][n][j] + b1v[n];
        x = fmaxf(x, 0.f);
        v += x * w2v[n];
      }
#pragma unroll
      for (int d = 1; d < 16; d <<= 1) v += __shfl_xor(v, d, 64);
      if ((lane & 15) == 0)
        atomicAdd(&rowsum[m * 16 + (lane >> 4) * 4 + j], v);
    }
  __syncthreads();
  if (tid < 64) {
    out[bm * 64 + tid] = rowsum[tid] + b2[0];  // OUTPUT IS FLOAT32
  }
}

// ---------------------------------------------------------------------------
extern "C" void kernel_launch(void* const* d_in, const int* in_sizes, int n_in,
                              void* d_out, int out_size, void* d_ws, size_t ws_size,
                              hipStream_t stream) {
  const float* whiteF = (const float*)d_in[0];
  const float* blackF = (const float*)d_in[1];
  const float* ftw    = (const float*)d_in[2];
  const float* ftb    = (const float*)d_in[3];
  const float* w1     = (const float*)d_in[4];
  const float* b1     = (const float*)d_in[5];
  const float* w2     = (const float*)d_in[6];
  const float* b2     = (const float*)d_in[7];

  const size_t per_split  = (size_t)2 * BATCH * H1 * sizeof(float);     // 16.8MB
  const size_t comb_bytes = (size_t)BATCH * 1024 * sizeof(unsigned short);
  int KS = 8;
  while (KS > 1 && (size_t)KS * per_split + comb_bytes > ws_size) KS >>= 1;

  float* Ppart = (float*)d_ws;
  unsigned short* comb = (unsigned short*)((char*)d_ws + (size_t)KS * per_split);
  float* outp = (float*)d_out;

  hipLaunchKernelGGL(ft_gemm_kernel, dim3(64 * KS), dim3(512), 0, stream,
                     whiteF, blackF, ftw, Ppart, KS);
  hipLaunchKernelGGL(ft_reduce_kernel, dim3((2 * BATCH * H1 / 4) / 256), dim3(256),
                     0, stream, Ppart, ftb, comb, KS);
  hipLaunchKernelGGL(fc_kernel, dim3(BATCH / 64), dim3(256), 0, stream,
                     comb, w1, b1, w2, b2, outp);
}

// Round 4
// 584.649 us; speedup vs baseline: 1.1456x; 1.1456x over previous
//
#include <hip/hip_runtime.h>
#include <stdint.h>

#define BATCH 4096
#define FEAT  40960
#define H1    512
#define KS    4
#define KCHUNK (FEAT / KS)    // 10240
#define NSTEPS (KCHUNK / 32)  // 320
#define NTILES (FEAT / 32)    // 1280
#define WTILE  32768          // bytes per pre-swizzled W k-tile (512 rows x 32 bf16)

typedef float f32x4 __attribute__((ext_vector_type(4)));
typedef short s16x8 __attribute__((ext_vector_type(8)));
typedef unsigned int u32x2 __attribute__((ext_vector_type(2)));
typedef unsigned int u32x4 __attribute__((ext_vector_type(4)));

// round-to-nearest-even f32 -> bf16, packed pair (lo in low 16 bits)
__device__ __forceinline__ unsigned bfpack2(float lo, float hi) {
  unsigned a = __float_as_uint(lo);
  unsigned b = __float_as_uint(hi);
  a += 0x7FFFu + ((a >> 16) & 1u);
  b += 0x7FFFu + ((b >> 16) & 1u);
  return (a >> 16) | (b & 0xFFFF0000u);
}

// Swizzle for 64B-row LDS tiles, 16B chunk granularity: chunk ^= (r>>1)&3.
// A 16-lane fragment read (rows R..R+15, fixed chunk) maps to bank-quads
// (16*(r&1) + 4*((c/16)^((r>>1)&3))): all 8 quads hit exactly twice ->
// 2-way, which is free (m136). Bijective; preserves 16B alignment.
__device__ __forceinline__ int lds_swz(int r, int cb) {
  return (r << 6) + (cb ^ (((r >> 1) & 3) << 4));
}

// async global->LDS, 16B per lane; LDS dest = wave-uniform base + lane*16.
__device__ __forceinline__ void glds16(const void* g, void* l) {
  __builtin_amdgcn_global_load_lds(
      (const __attribute__((address_space(1))) unsigned*)g,
      (__attribute__((address_space(3))) unsigned*)l, 16, 0, 0);
}

// ---------------------------------------------------------------------------
// Kernel 0: one-time ftw f32 -> bf16, stored as 1280 ready-made 32KB LDS tile
// images (pre-swizzled source for global_load_lds, rule #21).
// wbf[T][lds_swz(r, chunk*16)] = bf16(ftw[r][T*32 + chunk*8 .. +8])
// ---------------------------------------------------------------------------
__global__ __launch_bounds__(512)
void wcvt_kernel(const float* __restrict__ ftw, char* __restrict__ wbf) {
  const int bid = blockIdx.x;  // NTILES*4
  const int T = bid >> 2, rq = bid & 3;
  const int tid = threadIdx.x;
  const int r = rq * 128 + (tid >> 2), kq = tid & 3;
  const float* src = ftw + (size_t)r * FEAT + T * 32 + kq * 8;
  f32x4 v0 = *(const f32x4*)src;
  f32x4 v1 = *(const f32x4*)(src + 4);
  u32x4 o;
  o.x = bfpack2(v0.x, v0.y); o.y = bfpack2(v0.z, v0.w);
  o.z = bfpack2(v1.x, v1.y); o.w = bfpack2(v1.z, v1.w);
  *(u32x4*)(wbf + (size_t)T * WTILE + lds_swz(r, kq * 16)) = o;
}

// ---------------------------------------------------------------------------
// Kernel 1: feature-transform GEMM, split-K partials.
// BM=128 BN=512 BK=32, 512 thr (8 waves 2x4). A reg-staged f32->bf16;
// W staged via global_load_lds from pre-swizzled wbf. Counted-vmcnt pipeline:
// raw barrier, W-DMA for t+1 issued post-barrier under MFMA(t), A(t+1) loads
// stay in flight across the barrier (vmcnt(2)).
// ---------------------------------------------------------------------------
__global__ __launch_bounds__(512, 2)
void ft_gemm_kernel(const float* __restrict__ whiteF,
                    const float* __restrict__ blackF,
                    const char* __restrict__ wbf,
                    float* __restrict__ Ppart) {
  __shared__ char smem[81920];  // 2 x (A 8KB @0 | W 32KB @8192)

  const int tid = threadIdx.x, bid = blockIdx.x;
  const int ks = bid >> 6;         // k-split (0..3)
  const int p  = bid & 1;          // perspective
  const int mt = (bid >> 1) & 31;  // m-tile

  const float* Ag =
      (p == 0 ? whiteF : blackF) + (size_t)(mt * 128) * FEAT + ks * KCHUNK;

  const int a_row = tid >> 2, a_kq = tid & 3;  // A: 128 rows x 4 chunks of 8 f32
  const float* aptr = Ag + (size_t)a_row * FEAT + a_kq * 8;
  const int awoff = lds_swz(a_row, a_kq * 16);

  const int lane = tid & 63, wave = tid >> 6;
  const char* wsrc = wbf + (size_t)(ks * NSTEPS) * WTILE + wave * 4096 + lane * 16;
  const int wdst = 8192 + wave * 4096;  // + B*40960 + c*1024

  // wave tile 64x128 (2M x 4N); fragment offsets
  const int wm = wave >> 2, wn = wave & 3;
  const int lrow = lane & 15, lkb = (lane >> 4) * 16;
  int a_off[4], b_off[8];
#pragma unroll
  for (int m = 0; m < 4; ++m) a_off[m] = lds_swz(wm * 64 + m * 16 + lrow, lkb);
#pragma unroll
  for (int n = 0; n < 8; ++n) b_off[n] = 8192 + lds_swz(wn * 128 + n * 16 + lrow, lkb);

  f32x4 acc[4][8];
#pragma unroll
  for (int m = 0; m < 4; ++m)
#pragma unroll
    for (int n = 0; n < 8; ++n) acc[m][n] = (f32x4){0.f, 0.f, 0.f, 0.f};

  f32x4 raA[2], raB[2];

  // prologue: W tile 0 -> buf0 (DMA), A tile 0 -> regset 0
#pragma unroll
  for (int c = 0; c < 4; ++c) glds16(wsrc + c * 1024, smem + wdst + c * 1024);
  raA[0] = *(const f32x4*)aptr;
  raB[0] = *(const f32x4*)(aptr + 4);

  // Steady-state vmem queue at GSTEP(B,t) entry: [A(t):2][W(t):4].
  // In-step: +A(t+1):2 -> cvt auto-waits vmcnt(6); manual vmcnt(2) completes
  // W(t) leaving A(t+1) in flight; post-barrier issue W(t+1):4 under MFMA.
#define GSTEP(B, LAST, t)                                                     \
  {                                                                           \
    if (!(LAST)) {                                                            \
      const float* ap = aptr + (size_t)((t) + 1) * 32;                        \
      raA[(B) ^ 1] = *(const f32x4*)ap;                                       \
      raB[(B) ^ 1] = *(const f32x4*)(ap + 4);                                 \
    }                                                                         \
    u32x4 av;                                                                 \
    av.x = bfpack2(raA[B].x, raA[B].y); av.y = bfpack2(raA[B].z, raA[B].w);   \
    av.z = bfpack2(raB[B].x, raB[B].y); av.w = bfpack2(raB[B].z, raB[B].w);   \
    *(u32x4*)(smem + (B) * 40960 + awoff) = av;                               \
    __builtin_amdgcn_sched_barrier(0);                                        \
    if (LAST) { asm volatile("s_waitcnt vmcnt(0) lgkmcnt(0)" ::: "memory"); } \
    else      { asm volatile("s_waitcnt vmcnt(2) lgkmcnt(0)" ::: "memory"); } \
    __builtin_amdgcn_sched_barrier(0);                                        \
    __builtin_amdgcn_s_barrier();                                             \
    __builtin_amdgcn_sched_barrier(0);                                        \
    const char* base = smem + (B) * 40960;                                    \
    s16x8 af[4];                                                              \
    _Pragma("unroll") for (int m = 0; m < 4; ++m)                             \
        af[m] = *(const s16x8*)(base + a_off[m]);                             \
    s16x8 bfr[8];                                                             \
    _Pragma("unroll") for (int n = 0; n < 8; ++n)                             \
        bfr[n] = *(const s16x8*)(base + b_off[n]);                            \
    if (!(LAST)) {                                                            \
      const char* wsp = wsrc + (size_t)((t) + 1) * WTILE;                     \
      char* wdp = smem + ((B) ^ 1) * 40960 + wdst;                            \
      _Pragma("unroll") for (int c = 0; c < 4; ++c)                           \
          glds16(wsp + c * 1024, wdp + c * 1024);                             \
    }                                                                         \
    _Pragma("unroll") for (int n = 0; n < 8; ++n)                             \
      _Pragma("unroll") for (int m = 0; m < 4; ++m)                           \
          acc[m][n] = __builtin_amdgcn_mfma_f32_16x16x32_bf16(                \
              af[m], bfr[n], acc[m][n], 0, 0, 0);                             \
  }

  for (int tt = 0; tt < NSTEPS - 2; tt += 2) {
    GSTEP(0, false, tt);
    GSTEP(1, false, tt + 1);
  }
  GSTEP(0, false, NSTEPS - 2);
  GSTEP(1, true, NSTEPS - 1);
#undef GSTEP

  // write partials: C/D frag: col = lane&15, row = (lane>>4)*4 + j
  float* Pp = Ppart + ((size_t)(ks * 2 + p) * BATCH + mt * 128) * H1;
  const int r0 = wm * 64 + (lane >> 4) * 4;
  const int c0 = wn * 128 + lrow;
#pragma unroll
  for (int m = 0; m < 4; ++m)
#pragma unroll
    for (int n = 0; n < 8; ++n) {
      float* dst = Pp + (size_t)(r0 + m * 16) * H1 + c0 + n * 16;
#pragma unroll
      for (int j = 0; j < 4; ++j) dst[(size_t)j * H1] = acc[m][n][j];
    }
}

// ---------------------------------------------------------------------------
// Kernel 2: reduce split-K partials + bias + clip[0,1] -> combined bf16
// ---------------------------------------------------------------------------
__global__ __launch_bounds__(256)
void ft_reduce_kernel(const float* __restrict__ Ppart,
                      const float* __restrict__ ftb,
                      unsigned short* __restrict__ comb) {
  const size_t gid = (size_t)blockIdx.x * 256 + threadIdx.x;  // 2*B*H1/4
  const int    pp  = (int)(gid / (BATCH * H1 / 4));
  const size_t rem = gid % (BATCH * H1 / 4);
  const int    row = (int)(rem / (H1 / 4));
  const int    n4  = (int)(rem % (H1 / 4)) * 4;

  f32x4 s = (f32x4){0.f, 0.f, 0.f, 0.f};
#pragma unroll
  for (int ks = 0; ks < KS; ++ks)
    s += *(const f32x4*)(Ppart + ((size_t)(ks * 2 + pp) * BATCH + row) * H1 + n4);
  const f32x4 bv = *(const f32x4*)(ftb + n4);
  s += bv;
  s.x = fminf(fmaxf(s.x, 0.f), 1.f);
  s.y = fminf(fmaxf(s.y, 0.f), 1.f);
  s.z = fminf(fmaxf(s.z, 0.f), 1.f);
  s.w = fminf(fmaxf(s.w, 0.f), 1.f);

  u32x2 o;
  o.x = bfpack2(s.x, s.y);
  o.y = bfpack2(s.z, s.w);
  *(u32x2*)(comb + (size_t)row * 1024 + pp * H1 + n4) = o;
}

// ---------------------------------------------------------------------------
// Kernel 3: fc1 (bf16 MFMA) + relu + fc2 dot + bias -> out FLOAT32 [4096]
// ---------------------------------------------------------------------------
__global__ __launch_bounds__(256)
void fc_kernel(const unsigned short* __restrict__ comb,
               const float* __restrict__ w1, const float* __restrict__ b1,
               const float* __restrict__ w2, const float* __restrict__ b2,
               float* __restrict__ out) {
  __shared__ char smem[40960];  // 2 x (A 4KB + W 16KB)
  __shared__ float rowsum[64];

  const int tid = threadIdx.x;
  const int bm  = blockIdx.x;  // 64 blocks of 64 rows
  if (tid < 64) rowsum[tid] = 0.f;

  const int a_row = tid >> 2, a_kq = tid & 3;
  const unsigned short* aptr = comb + (size_t)(bm * 64 + a_row) * 1024 + a_kq * 8;
  const float* wptr = w1 + (size_t)a_row * 1024 + a_kq * 8;

  u32x4 raA;
  f32x4 rw0[4], rw1[4];
  auto issue = [&](int t) {
    raA = *(const u32x4*)(aptr + t * 32);
    const float* wp = wptr + t * 32;
#pragma unroll
    for (int s = 0; s < 4; ++s) {
      rw0[s] = *(const f32x4*)(wp + (size_t)s * 64 * 1024);
      rw1[s] = *(const f32x4*)(wp + (size_t)s * 64 * 1024 + 4);
    }
  };

  const int aoff_w = lds_swz(a_row, a_kq * 16);
  int woff_w[4];
#pragma unroll
  for (int s = 0; s < 4; ++s)
    woff_w[s] = 4096 + lds_swz(s * 64 + a_row, a_kq * 16);

  auto cvtwrite = [&](int b) {
    char* base = smem + b * 20480;
    *(u32x4*)(base + aoff_w) = raA;
#pragma unroll
    for (int s = 0; s < 4; ++s) {
      u32x4 wv;
      wv.x = bfpack2(rw0[s].x, rw0[s].y); wv.y = bfpack2(rw0[s].z, rw0[s].w);
      wv.z = bfpack2(rw1[s].x, rw1[s].y); wv.w = bfpack2(rw1[s].z, rw1[s].w);
      *(u32x4*)(base + woff_w[s]) = wv;
    }
  };

  const int lane = tid & 63, wn = tid >> 6;
  const int lrow = lane & 15, lkb = (lane >> 4) * 16;
  int a_off[4], b_off[4];
#pragma unroll
  for (int m = 0; m < 4; ++m) a_off[m] = lds_swz(m * 16 + lrow, lkb);
#pragma unroll
  for (int n = 0; n < 4; ++n) b_off[n] = 4096 + lds_swz(wn * 64 + n * 16 + lrow, lkb);

  f32x4 acc[4][4];
#pragma unroll
  for (int m = 0; m < 4; ++m)
#pragma unroll
    for (int n = 0; n < 4; ++n) acc[m][n] = (f32x4){0.f, 0.f, 0.f, 0.f};

  issue(0);
  for (int t = 0; t < 32; ++t) {
    const int b = t & 1;
    cvtwrite(b);
    if (t + 1 < 32) issue(t + 1);
    asm volatile("s_waitcnt lgkmcnt(0)" ::: "memory");
    __builtin_amdgcn_sched_barrier(0);
    __builtin_amdgcn_s_barrier();
    __builtin_amdgcn_sched_barrier(0);
    char* base = smem + b * 20480;
    s16x8 af[4];
#pragma unroll
    for (int m = 0; m < 4; ++m) af[m] = *(const s16x8*)(base + a_off[m]);
#pragma unroll
    for (int n = 0; n < 4; ++n) {
      s16x8 bfn = *(const s16x8*)(base + b_off[n]);
#pragma unroll
      for (int m = 0; m < 4; ++m)
        acc[m][n] = __builtin_amdgcn_mfma_f32_16x16x32_bf16(af[m], bfn, acc[m][n], 0, 0, 0);
    }
  }

  float b1v[4], w2v[4];
#pragma unroll
  for (int n = 0; n < 4; ++n) {
    const int col = wn * 64 + n * 16 + lrow;
    b1v[n] = b1[col];
    w2v[n] = w2[col];
  }
#pragma unroll
  for (int m = 0; m < 4; ++m)
#pragma unroll
    for (int j = 0; j < 4; ++j) {
      float v = 0.f;
#pragma unroll
      for (int n = 0; n < 4; ++n) {
        float x = acc[m][n][j] + b1v[n];
        x = fmaxf(x, 0.f);
        v += x * w2v[n];
      }
#pragma unroll
      for (int d = 1; d < 16; d <<= 1) v += __shfl_xor(v, d, 64);
      if ((lane & 15) == 0)
        atomicAdd(&rowsum[m * 16 + (lane >> 4) * 4 + j], v);
    }
  __syncthreads();
  if (tid < 64) {
    out[bm * 64 + tid] = rowsum[tid] + b2[0];  // f32 output
  }
}

// ---------------------------------------------------------------------------
extern "C" void kernel_launch(void* const* d_in, const int* in_sizes, int n_in,
                              void* d_out, int out_size, void* d_ws, size_t ws_size,
                              hipStream_t stream) {
  const float* whiteF = (const float*)d_in[0];
  const float* blackF = (const float*)d_in[1];
  const float* ftw    = (const float*)d_in[2];
  const float* ftb    = (const float*)d_in[3];
  const float* w1     = (const float*)d_in[4];
  const float* b1     = (const float*)d_in[5];
  const float* w2     = (const float*)d_in[6];
  const float* b2     = (const float*)d_in[7];

  char* wbf = (char*)d_ws;                                   // 41,943,040 B
  const size_t wbf_bytes   = (size_t)NTILES * WTILE;
  const size_t ppart_bytes = (size_t)KS * 2 * BATCH * H1 * sizeof(float);
  float* Ppart = (float*)((char*)d_ws + wbf_bytes);
  unsigned short* comb = (unsigned short*)((char*)d_ws + wbf_bytes + ppart_bytes);
  float* outp = (float*)d_out;

  hipLaunchKernelGGL(wcvt_kernel, dim3(NTILES * 4), dim3(512), 0, stream, ftw, wbf);
  hipLaunchKernelGGL(ft_gemm_kernel, dim3(64 * KS), dim3(512), 0, stream,
                     whiteF, blackF, wbf, Ppart);
  hipLaunchKernelGGL(ft_reduce_kernel, dim3((2 * BATCH * H1 / 4) / 256), dim3(256),
                     0, stream, Ppart, ftb, comb);
  hipLaunchKernelGGL(fc_kernel, dim3(BATCH / 64), dim3(256), 0, stream,
                     comb, w1, b1, w2, b2, outp);
}

// Round 5
// 548.759 us; speedup vs baseline: 1.2205x; 1.0654x over previous
//
#include <hip/hip_runtime.h>
#include <stdint.h>

#define BATCH 4096
#define FEAT  40960
#define H1    512
#define KS    4
#define KCHUNK (FEAT / KS)    // 10240
#define NSTEPS (KCHUNK / 32)  // 320
#define NTILES (FEAT / 32)    // 1280
#define WTILE  32768          // bytes per pre-swizzled W k-tile (512 rows x 32 bf16)
#define BUFSTRIDE 36864       // W 32KB @0 | A 4KB @32768
#define ALDS 32768

typedef float f32x4 __attribute__((ext_vector_type(4)));
typedef short s16x8 __attribute__((ext_vector_type(8)));
typedef unsigned int u32x2 __attribute__((ext_vector_type(2)));
typedef unsigned int u32x4 __attribute__((ext_vector_type(4)));

// round-to-nearest-even f32 -> bf16, packed pair (lo in low 16 bits)
__device__ __forceinline__ unsigned bfpack2(float lo, float hi) {
  unsigned a = __float_as_uint(lo);
  unsigned b = __float_as_uint(hi);
  a += 0x7FFFu + ((a >> 16) & 1u);
  b += 0x7FFFu + ((b >> 16) & 1u);
  return (a >> 16) | (b & 0xFFFF0000u);
}

// Swizzle for 64B-row LDS tiles, 16B chunk granularity: chunk ^= (r>>1)&3.
// 16-lane fragment reads (rows R..R+15, fixed chunk) hit all 8 bank-quads
// exactly twice -> 2-way (free, m136). Bijective; preserves 8B alignment.
__device__ __forceinline__ int lds_swz(int r, int cb) {
  return (r << 6) + (cb ^ (((r >> 1) & 3) << 4));
}

// async global->LDS, 16B per lane; LDS dest = wave-uniform base + lane*16.
__device__ __forceinline__ void glds16(const void* g, void* l) {
  __builtin_amdgcn_global_load_lds(
      (const __attribute__((address_space(1))) unsigned*)g,
      (__attribute__((address_space(3))) unsigned*)l, 16, 0, 0);
}

// ---------------------------------------------------------------------------
// Kernel 0: one-time ftw f32 -> bf16, stored as 1280 ready-made 32KB LDS tile
// images (pre-swizzled source for global_load_lds, rule #21).
// ---------------------------------------------------------------------------
__global__ __launch_bounds__(512)
void wcvt_kernel(const float* __restrict__ ftw, char* __restrict__ wbf) {
  const int bid = blockIdx.x;  // NTILES*4
  const int T = bid >> 2, rq = bid & 3;
  const int tid = threadIdx.x;
  const int r = rq * 128 + (tid >> 2), kq = tid & 3;
  const float* src = ftw + (size_t)r * FEAT + T * 32 + kq * 8;
  f32x4 v0 = *(const f32x4*)src;
  f32x4 v1 = *(const f32x4*)(src + 4);
  u32x4 o;
  o.x = bfpack2(v0.x, v0.y); o.y = bfpack2(v0.z, v0.w);
  o.z = bfpack2(v1.x, v1.y); o.w = bfpack2(v1.z, v1.w);
  *(u32x4*)(wbf + (size_t)T * WTILE + lds_swz(r, kq * 16)) = o;
}

// ---------------------------------------------------------------------------
// Kernel 1: feature-transform GEMM, split-K partials.
// BM=64 BN=512 BK=32, 512 thr = 8 waves (1M x 8N), wave tile 64x64.
// LDS 72KB (2 x [W 32KB | A 4KB]) -> 2 blocks/CU = 4 waves/SIMD.
// A reg->cvt->LDS; W via global_load_lds from pre-swizzled wbf.
// Counted vmcnt: per-thread queue [W(t):4, A(t+1):1] -> wait vmcnt(1).
// XCD-chunked remap: all 64 blocks of an XCD stream one W k-region (L2-hot).
// ---------------------------------------------------------------------------
__global__ __launch_bounds__(512, 4)
void ft_gemm_kernel(const float* __restrict__ whiteF,
                    const float* __restrict__ blackF,
                    const char* __restrict__ wbf,
                    float* __restrict__ Ppart) {
  __shared__ char smem[2 * BUFSTRIDE];

  const int tid = threadIdx.x, bid = blockIdx.x;
  const int wgid = (bid & 7) * 64 + (bid >> 3);  // bijective, 512 blocks
  const int ks = wgid >> 7;         // 0..3
  const int p  = (wgid >> 6) & 1;   // perspective
  const int mt = wgid & 63;         // m-tile (64 rows)

  const float* Ag =
      (p == 0 ? whiteF : blackF) + (size_t)(mt * 64) * FEAT + ks * KCHUNK;

  // A staging: 64 rows x 8 threads/row x 4 f32
  const int a_row = tid >> 3, a_kq = tid & 7;
  const float* aptr = Ag + (size_t)a_row * FEAT + a_kq * 4;
  const int awoff = ALDS + lds_swz(a_row, a_kq * 8);

  const int lane = tid & 63, wave = tid >> 6;
  const char* wsrc = wbf + (size_t)ks * NSTEPS * WTILE + wave * 4096 + lane * 16;
  const int wdst = wave * 4096;

  // wave tile 64x64: all waves share A rows 0..63; wave `wave` owns W cols
  const int wn = wave;
  const int lrow = lane & 15, lkb = (lane >> 4) * 16;
  int a_off[4], b_off[4];
#pragma unroll
  for (int m = 0; m < 4; ++m) a_off[m] = ALDS + lds_swz(m * 16 + lrow, lkb);
#pragma unroll
  for (int n = 0; n < 4; ++n) b_off[n] = lds_swz(wn * 64 + n * 16 + lrow, lkb);

  f32x4 acc[4][4];
#pragma unroll
  for (int m = 0; m < 4; ++m)
#pragma unroll
    for (int n = 0; n < 4; ++n) acc[m][n] = (f32x4){0.f, 0.f, 0.f, 0.f};

  f32x4 raA[2];

  // prologue: W(0) DMA -> buf0, A(0) -> regset 0
#pragma unroll
  for (int c = 0; c < 4; ++c) glds16(wsrc + c * 1024, smem + wdst + c * 1024);
  raA[0] = *(const f32x4*)aptr;

#define GSTEP(B, LAST, t)                                                     \
  {                                                                           \
    if (!(LAST)) raA[(B) ^ 1] = *(const f32x4*)(aptr + (size_t)((t) + 1) * 32); \
    u32x2 av;                                                                 \
    av.x = bfpack2(raA[B].x, raA[B].y);                                       \
    av.y = bfpack2(raA[B].z, raA[B].w);                                       \
    *(u32x2*)(smem + (B) * BUFSTRIDE + awoff) = av;                           \
    __builtin_amdgcn_sched_barrier(0);                                        \
    if (LAST) { asm volatile("s_waitcnt vmcnt(0) lgkmcnt(0)" ::: "memory"); } \
    else      { asm volatile("s_waitcnt vmcnt(1) lgkmcnt(0)" ::: "memory"); } \
    __builtin_amdgcn_sched_barrier(0);                                        \
    __builtin_amdgcn_s_barrier();                                             \
    __builtin_amdgcn_sched_barrier(0);                                        \
    const char* base = smem + (B) * BUFSTRIDE;                                \
    s16x8 af[4];                                                              \
    _Pragma("unroll") for (int m = 0; m < 4; ++m)                             \
        af[m] = *(const s16x8*)(base + a_off[m]);                             \
    if (!(LAST)) {                                                            \
      const char* wsp = wsrc + (size_t)((t) + 1) * WTILE;                     \
      char* wdp = smem + ((B) ^ 1) * BUFSTRIDE + wdst;                        \
      _Pragma("unroll") for (int c = 0; c < 4; ++c)                           \
          glds16(wsp + c * 1024, wdp + c * 1024);                             \
    }                                                                         \
    _Pragma("unroll") for (int n = 0; n < 4; ++n) {                           \
      s16x8 bfn = *(const s16x8*)(base + b_off[n]);                           \
      _Pragma("unroll") for (int m = 0; m < 4; ++m)                           \
          acc[m][n] = __builtin_amdgcn_mfma_f32_16x16x32_bf16(                \
              af[m], bfn, acc[m][n], 0, 0, 0);                                \
    }                                                                         \
  }

  for (int tt = 0; tt < NSTEPS - 2; tt += 2) {
    GSTEP(0, false, tt);
    GSTEP(1, false, tt + 1);
  }
  GSTEP(0, false, NSTEPS - 2);
  GSTEP(1, true, NSTEPS - 1);
#undef GSTEP

  // C/D frag: col = lane&15, row = (lane>>4)*4 + j
  float* Pp = Ppart + ((size_t)(ks * 2 + p) * BATCH + mt * 64) * H1;
  const int r0 = (lane >> 4) * 4;
  const int c0 = wn * 64 + lrow;
#pragma unroll
  for (int m = 0; m < 4; ++m)
#pragma unroll
    for (int n = 0; n < 4; ++n) {
      float* dst = Pp + (size_t)(r0 + m * 16) * H1 + c0 + n * 16;
#pragma unroll
      for (int j = 0; j < 4; ++j) dst[(size_t)j * H1] = acc[m][n][j];
    }
}

// ---------------------------------------------------------------------------
// Kernel 2: reduce split-K partials + bias + clip[0,1] -> combined bf16
// ---------------------------------------------------------------------------
__global__ __launch_bounds__(256)
void ft_reduce_kernel(const float* __restrict__ Ppart,
                      const float* __restrict__ ftb,
                      unsigned short* __restrict__ comb) {
  const size_t gid = (size_t)blockIdx.x * 256 + threadIdx.x;  // 2*B*H1/4
  const int    pp  = (int)(gid / (BATCH * H1 / 4));
  const size_t rem = gid % (BATCH * H1 / 4);
  const int    row = (int)(rem / (H1 / 4));
  const int    n4  = (int)(rem % (H1 / 4)) * 4;

  f32x4 s = (f32x4){0.f, 0.f, 0.f, 0.f};
#pragma unroll
  for (int ks = 0; ks < KS; ++ks)
    s += *(const f32x4*)(Ppart + ((size_t)(ks * 2 + pp) * BATCH + row) * H1 + n4);
  const f32x4 bv = *(const f32x4*)(ftb + n4);
  s += bv;
  s.x = fminf(fmaxf(s.x, 0.f), 1.f);
  s.y = fminf(fmaxf(s.y, 0.f), 1.f);
  s.z = fminf(fmaxf(s.z, 0.f), 1.f);
  s.w = fminf(fmaxf(s.w, 0.f), 1.f);

  u32x2 o;
  o.x = bfpack2(s.x, s.y);
  o.y = bfpack2(s.z, s.w);
  *(u32x2*)(comb + (size_t)row * 1024 + pp * H1 + n4) = o;
}

// ---------------------------------------------------------------------------
// Kernel 3: fc1 (bf16 MFMA) + relu + fc2 dot + bias -> out FLOAT32 [4096]
// ---------------------------------------------------------------------------
__global__ __launch_bounds__(256)
void fc_kernel(const unsigned short* __restrict__ comb,
               const float* __restrict__ w1, const float* __restrict__ b1,
               const float* __restrict__ w2, const float* __restrict__ b2,
               float* __restrict__ out) {
  __shared__ char smem[40960];  // 2 x (A 4KB + W 16KB)
  __shared__ float rowsum[64];

  const int tid = threadIdx.x;
  const int bm  = blockIdx.x;  // 64 blocks of 64 rows
  if (tid < 64) rowsum[tid] = 0.f;

  const int a_row = tid >> 2, a_kq = tid & 3;
  const unsigned short* aptr = comb + (size_t)(bm * 64 + a_row) * 1024 + a_kq * 8;
  const float* wptr = w1 + (size_t)a_row * 1024 + a_kq * 8;

  u32x4 raA;
  f32x4 rw0[4], rw1[4];
  auto issue = [&](int t) {
    raA = *(const u32x4*)(aptr + t * 32);
    const float* wp = wptr + t * 32;
#pragma unroll
    for (int s = 0; s < 4; ++s) {
      rw0[s] = *(const f32x4*)(wp + (size_t)s * 64 * 1024);
      rw1[s] = *(const f32x4*)(wp + (size_t)s * 64 * 1024 + 4);
    }
  };

  const int aoff_w = lds_swz(a_row, a_kq * 16);
  int woff_w[4];
#pragma unroll
  for (int s = 0; s < 4; ++s)
    woff_w[s] = 4096 + lds_swz(s * 64 + a_row, a_kq * 16);

  auto cvtwrite = [&](int b) {
    char* base = smem + b * 20480;
    *(u32x4*)(base + aoff_w) = raA;
#pragma unroll
    for (int s = 0; s < 4; ++s) {
      u32x4 wv;
      wv.x = bfpack2(rw0[s].x, rw0[s].y); wv.y = bfpack2(rw0[s].z, rw0[s].w);
      wv.z = bfpack2(rw1[s].x, rw1[s].y); wv.w = bfpack2(rw1[s].z, rw1[s].w);
      *(u32x4*)(base + woff_w[s]) = wv;
    }
  };

  const int lane = tid & 63, wn = tid >> 6;
  const int lrow = lane & 15, lkb = (lane >> 4) * 16;
  int a_off[4], b_off[4];
#pragma unroll
  for (int m = 0; m < 4; ++m) a_off[m] = lds_swz(m * 16 + lrow, lkb);
#pragma unroll
  for (int n = 0; n < 4; ++n) b_off[n] = 4096 + lds_swz(wn * 64 + n * 16 + lrow, lkb);

  f32x4 acc[4][4];
#pragma unroll
  for (int m = 0; m < 4; ++m)
#pragma unroll
    for (int n = 0; n < 4; ++n) acc[m][n] = (f32x4){0.f, 0.f, 0.f, 0.f};

  issue(0);
  for (int t = 0; t < 32; ++t) {
    const int b = t & 1;
    cvtwrite(b);
    if (t + 1 < 32) issue(t + 1);
    asm volatile("s_waitcnt lgkmcnt(0)" ::: "memory");
    __builtin_amdgcn_sched_barrier(0);
    __builtin_amdgcn_s_barrier();
    __builtin_amdgcn_sched_barrier(0);
    char* base = smem + b * 20480;
    s16x8 af[4];
#pragma unroll
    for (int m = 0; m < 4; ++m) af[m] = *(const s16x8*)(base + a_off[m]);
#pragma unroll
    for (int n = 0; n < 4; ++n) {
      s16x8 bfn = *(const s16x8*)(base + b_off[n]);
#pragma unroll
      for (int m = 0; m < 4; ++m)
        acc[m][n] = __builtin_amdgcn_mfma_f32_16x16x32_bf16(af[m], bfn, acc[m][n], 0, 0, 0);
    }
  }

  float b1v[4], w2v[4];
#pragma unroll
  for (int n = 0; n < 4; ++n) {
    const int col = wn * 64 + n * 16 + lrow;
    b1v[n] = b1[col];
    w2v[n] = w2[col];
  }
#pragma unroll
  for (int m = 0; m < 4; ++m)
#pragma unroll
    for (int j = 0; j < 4; ++j) {
      float v = 0.f;
#pragma unroll
      for (int n = 0; n < 4; ++n) {
        float x = acc[m][n][j] + b1v[n];
        x = fmaxf(x, 0.f);
        v += x * w2v[n];
      }
#pragma unroll
      for (int d = 1; d < 16; d <<= 1) v += __shfl_xor(v, d, 64);
      if ((lane & 15) == 0)
        atomicAdd(&rowsum[m * 16 + (lane >> 4) * 4 + j], v);
    }
  __syncthreads();
  if (tid < 64) {
    out[bm * 64 + tid] = rowsum[tid] + b2[0];  // f32 output
  }
}

// ---------------------------------------------------------------------------
extern "C" void kernel_launch(void* const* d_in, const int* in_sizes, int n_in,
                              void* d_out, int out_size, void* d_ws, size_t ws_size,
                              hipStream_t stream) {
  const float* whiteF = (const float*)d_in[0];
  const float* blackF = (const float*)d_in[1];
  const float* ftw    = (const float*)d_in[2];
  const float* ftb    = (const float*)d_in[3];
  const float* w1     = (const float*)d_in[4];
  const float* b1     = (const float*)d_in[5];
  const float* w2     = (const float*)d_in[6];
  const float* b2     = (const float*)d_in[7];

  char* wbf = (char*)d_ws;                                   // 41,943,040 B
  const size_t wbf_bytes   = (size_t)NTILES * WTILE;
  const size_t ppart_bytes = (size_t)KS * 2 * BATCH * H1 * sizeof(float);
  float* Ppart = (float*)((char*)d_ws + wbf_bytes);
  unsigned short* comb = (unsigned short*)((char*)d_ws + wbf_bytes + ppart_bytes);
  float* outp = (float*)d_out;

  hipLaunchKernelGGL(wcvt_kernel, dim3(NTILES * 4), dim3(512), 0, stream, ftw, wbf);
  hipLaunchKernelGGL(ft_gemm_kernel, dim3(512), dim3(512), 0, stream,
                     whiteF, blackF, wbf, Ppart);
  hipLaunchKernelGGL(ft_reduce_kernel, dim3((2 * BATCH * H1 / 4) / 256), dim3(256),
                     0, stream, Ppart, ftb, comb);
  hipLaunchKernelGGL(fc_kernel, dim3(BATCH / 64), dim3(256), 0, stream,
                     comb, w1, b1, w2, b2, outp);
}